// Round 5
// baseline (4342.392 us; speedup 1.0000x reference)
//
#include <hip/hip_runtime.h>

#define N_MET 100000
#define N_RXN 50000
#define E_SUB 2000000
#define E_ALL 4000000
#define MSG_DIM 16
#define HIDDEN 32

// ---- Phase 1: build CSR of substrate edges by reaction (counting sort), ----
// ---- then wave-per-reaction gather-reduce. -----------------------------------

// 1a. histogram of rxn_sub (int4-vectorized reads; E_SUB % 4 == 0)
__global__ __launch_bounds__(256) void hist_kernel(
    const int* __restrict__ rxn_sub, int* __restrict__ count)
{
    const int i = blockIdx.x * 256 + threadIdx.x;
    if (i >= E_SUB / 4) return;
    const int4 r = ((const int4*)rxn_sub)[i];
    atomicAdd(&count[r.x], 1);
    atomicAdd(&count[r.y], 1);
    atomicAdd(&count[r.z], 1);
    atomicAdd(&count[r.w], 1);
}

// 1b. exclusive scan of count[N_RXN] -> row_ptr[N_RXN+1], and next = row_ptr.
__global__ __launch_bounds__(1024) void scan_kernel(
    const int* __restrict__ count, int* __restrict__ row_ptr,
    int* __restrict__ next)
{
    __shared__ int wsum[16];
    const int t = threadIdx.x;
    const int lane = t & 63;
    const int w = t >> 6;
    int carry = 0;
    for (int base = 0; base < N_RXN; base += 1024) {
        const int idx = base + t;
        const int val = (idx < N_RXN) ? count[idx] : 0;
        int x = val;
#pragma unroll
        for (int off = 1; off < 64; off <<= 1) {
            const int y = __shfl_up(x, off);
            if (lane >= off) x += y;
        }
        if (lane == 63) wsum[w] = x;
        __syncthreads();
        if (w == 0) {
            int s = (lane < 16) ? wsum[lane] : 0;
#pragma unroll
            for (int off = 1; off < 16; off <<= 1) {
                const int y = __shfl_up(s, off);
                if (lane >= off) s += y;
            }
            if (lane < 16) wsum[lane] = s;
        }
        __syncthreads();
        const int wexcl = (w > 0) ? wsum[w - 1] : 0;
        const int excl = wexcl + x - val;
        if (idx < N_RXN) {
            const int rp = carry + excl;
            row_ptr[idx] = rp;
            next[idx] = rp;
        }
        carry += wsum[15];
        __syncthreads();
    }
    if (t == 0) row_ptr[N_RXN] = carry;
}

// 1c. placement: slot = next[r]++ ; edges_sorted[slot] = {x_met[met], sto}
__global__ __launch_bounds__(256) void place_kernel(
    const float* __restrict__ x_met, const float* __restrict__ sto_sub,
    const int* __restrict__ met_sub, const int* __restrict__ rxn_sub,
    int* __restrict__ next, float2* __restrict__ edges_sorted)
{
    const int e = blockIdx.x * 256 + threadIdx.x;
    if (e >= E_SUB) return;
    const int r = rxn_sub[e];
    const int slot = atomicAdd(&next[r], 1);
    edges_sorted[slot] = make_float2(x_met[met_sub[e]], sto_sub[e]);
}

// 1d. WAVE-PER-REACTION gather + msg-MLP + rate-MLP + softplus -> v[N_RXN].
// 64 lanes read the reaction's contiguous edge segment (coalesced); each lane
// runs the 2->32tanh->16 msg MLP for its edge(s) into registers; butterfly
// shfl reduce h[16] across the wave; rate MLP split 1 hidden unit/lane.
__global__ __launch_bounds__(256, 4) void gather_rate_kernel(
    const float2* __restrict__ edges_sorted, const int* __restrict__ row_ptr,
    const float* __restrict__ W1m, const float* __restrict__ b1m,
    const float* __restrict__ W2m, const float* __restrict__ b2m,
    const float* __restrict__ W1r, const float* __restrict__ b1r,
    const float* __restrict__ W2r, const float* __restrict__ b2r,
    float* __restrict__ v)
{
    __shared__ float sW1m[2 * HIDDEN];
    __shared__ float sb1m[HIDDEN];
    __shared__ float sW2m[HIDDEN * MSG_DIM];
    __shared__ float sb2m[MSG_DIM];
    __shared__ float sW1r[MSG_DIM * HIDDEN];
    __shared__ float sb1r[HIDDEN];
    __shared__ float sW2r[HIDDEN];
    __shared__ float sb2r;
    const int t = threadIdx.x;
    if (t < 2 * HIDDEN) sW1m[t] = W1m[t];
    if (t < HIDDEN)     sb1m[t] = b1m[t];
    for (int i = t; i < HIDDEN * MSG_DIM; i += 256) sW2m[i] = W2m[i];
    if (t < MSG_DIM)    sb2m[t] = b2m[t];
    for (int i = t; i < MSG_DIM * HIDDEN; i += 256) sW1r[i] = W1r[i];
    if (t >= 64 && t < 64 + HIDDEN) { sb1r[t - 64] = b1r[t - 64]; sW2r[t - 64] = W2r[t - 64]; }
    if (t == 128) sb2r = b2r[0];
    __syncthreads();

    const int wv   = t >> 6;
    const int lane = t & 63;
    const int r    = blockIdx.x * 4 + wv;   // grid = N_RXN/4 exactly

    const int beg = row_ptr[r];
    const int end = row_ptr[r + 1];

    float h[MSG_DIM];
#pragma unroll
    for (int d = 0; d < MSG_DIM; ++d) h[d] = 0.0f;

    for (int i = beg + lane; i < end; i += 64) {
        const float2 xs = edges_sorted[i];
#pragma unroll
        for (int j = 0; j < HIDDEN; ++j) {
            const float hj =
                tanhf(fmaf(xs.x, sW1m[j], fmaf(xs.y, sW1m[HIDDEN + j], sb1m[j])));
#pragma unroll
            for (int d = 0; d < MSG_DIM; ++d)
                h[d] = fmaf(hj, sW2m[j * MSG_DIM + d], h[d]);
        }
    }

    // wave-reduce h[16] (butterfly; all lanes end with the segment sum)
#pragma unroll
    for (int off = 32; off >= 1; off >>= 1) {
#pragma unroll
        for (int d = 0; d < MSG_DIM; ++d)
            h[d] += __shfl_xor(h[d], off);
    }

    // fold per-edge +b2m: cnt * b2m
    const float cnt = (float)(end - beg);
#pragma unroll
    for (int d = 0; d < MSG_DIM; ++d) h[d] = fmaf(cnt, sb2m[d], h[d]);

    // rate MLP: lane j (j<32) computes hidden unit j; reduce over 32 lanes
    float part = 0.0f;
    if (lane < HIDDEN) {
        float z = sb1r[lane];
#pragma unroll
        for (int d = 0; d < MSG_DIM; ++d)
            z = fmaf(h[d], sW1r[d * HIDDEN + lane], z);
        part = tanhf(z) * sW2r[lane];
    }
#pragma unroll
    for (int off = 16; off >= 1; off >>= 1)
        part += __shfl_xor(part, off);

    if (lane == 0) {
        const float acc = part + sb2r;
        v[r] = fmaxf(acc, 0.0f) + log1pf(expf(-fabsf(acc)));
    }
}

// ---- Phase 2: per-all-edge contribution scattered into dxdt (4M f32 atomics).
__global__ __launch_bounds__(256) void contrib_scatter_kernel(
    const float* __restrict__ sto_all, const float* __restrict__ v,
    const int* __restrict__ met_all, const int* __restrict__ rxn_all,
    float* __restrict__ dxdt)
{
    const int e = blockIdx.x * 256 + threadIdx.x;
    if (e >= E_ALL) return;
    const float c = sto_all[e] * v[rxn_all[e]];
    unsafeAtomicAdd(dxdt + met_all[e], c);
}

extern "C" void kernel_launch(void* const* d_in, const int* in_sizes, int n_in,
                              void* d_out, int out_size, void* d_ws, size_t ws_size,
                              hipStream_t stream) {
    const float* x_met   = (const float*)d_in[0];
    const float* sto_sub = (const float*)d_in[1];
    const float* sto_all = (const float*)d_in[2];
    const float* W1m     = (const float*)d_in[3];
    const float* b1m     = (const float*)d_in[4];
    const float* W2m     = (const float*)d_in[5];
    const float* b2m     = (const float*)d_in[6];
    const float* W1r     = (const float*)d_in[7];
    const float* b1r     = (const float*)d_in[8];
    const float* W2r     = (const float*)d_in[9];
    const float* b2r     = (const float*)d_in[10];
    const int*   met_sub = (const int*)d_in[11];
    const int*   rxn_sub = (const int*)d_in[12];
    const int*   met_all = (const int*)d_in[13];
    const int*   rxn_all = (const int*)d_in[14];

    float* dxdt = (float*)d_out;             // [N_MET]
    float* v    = dxdt + N_MET;              // [N_RXN]

    // workspace layout
    char* ws = (char*)d_ws;
    int* count   = (int*)ws;                              ws += sizeof(int) * N_RXN;
    int* row_ptr = (int*)ws;                              ws += sizeof(int) * (N_RXN + 1);
    int* next    = (int*)ws;                              ws += sizeof(int) * N_RXN;
    float2* edges_sorted = (float2*)ws;                   // [E_SUB] = 16 MB

    hipMemsetAsync(count, 0, sizeof(int) * N_RXN, stream);
    hipMemsetAsync(dxdt, 0, sizeof(float) * N_MET, stream);

    hist_kernel<<<(E_SUB / 4 + 255) / 256, 256, 0, stream>>>(rxn_sub, count);
    scan_kernel<<<1, 1024, 0, stream>>>(count, row_ptr, next);
    place_kernel<<<(E_SUB + 255) / 256, 256, 0, stream>>>(
        x_met, sto_sub, met_sub, rxn_sub, next, edges_sorted);
    gather_rate_kernel<<<N_RXN / 4, 256, 0, stream>>>(
        edges_sorted, row_ptr, W1m, b1m, W2m, b2m, W1r, b1r, W2r, b2r, v);
    contrib_scatter_kernel<<<(E_ALL + 255) / 256, 256, 0, stream>>>(
        sto_all, v, met_all, rxn_all, dxdt);
}

// Round 6
// 3010.051 us; speedup vs baseline: 1.4426x; 1.4426x over previous
//
#include <hip/hip_runtime.h>

#define N_MET 100000
#define N_RXN 50000
#define E_SUB 2000000
#define E_ALL 4000000
#define MSG_DIM 16
#define HIDDEN 32

// ---- Phase 1: build CSR of substrate edges by reaction (counting sort), ----
// ---- then wave-per-reaction gather-reduce. -----------------------------------

// 1a. histogram of rxn_sub (int4-vectorized reads; E_SUB % 4 == 0)
__global__ __launch_bounds__(256) void hist_kernel(
    const int* __restrict__ rxn_sub, int* __restrict__ count)
{
    const int i = blockIdx.x * 256 + threadIdx.x;
    if (i >= E_SUB / 4) return;
    const int4 r = ((const int4*)rxn_sub)[i];
    atomicAdd(&count[r.x], 1);
    atomicAdd(&count[r.y], 1);
    atomicAdd(&count[r.z], 1);
    atomicAdd(&count[r.w], 1);
}

// 1b. exclusive scan of count[N_RXN] -> row_ptr[N_RXN+1], and next = row_ptr.
__global__ __launch_bounds__(1024) void scan_kernel(
    const int* __restrict__ count, int* __restrict__ row_ptr,
    int* __restrict__ next)
{
    __shared__ int wsum[16];
    const int t = threadIdx.x;
    const int lane = t & 63;
    const int w = t >> 6;
    int carry = 0;
    for (int base = 0; base < N_RXN; base += 1024) {
        const int idx = base + t;
        const int val = (idx < N_RXN) ? count[idx] : 0;
        int x = val;
#pragma unroll
        for (int off = 1; off < 64; off <<= 1) {
            const int y = __shfl_up(x, off);
            if (lane >= off) x += y;
        }
        if (lane == 63) wsum[w] = x;
        __syncthreads();
        if (w == 0) {
            int s = (lane < 16) ? wsum[lane] : 0;
#pragma unroll
            for (int off = 1; off < 16; off <<= 1) {
                const int y = __shfl_up(s, off);
                if (lane >= off) s += y;
            }
            if (lane < 16) wsum[lane] = s;
        }
        __syncthreads();
        const int wexcl = (w > 0) ? wsum[w - 1] : 0;
        const int excl = wexcl + x - val;
        if (idx < N_RXN) {
            const int rp = carry + excl;
            row_ptr[idx] = rp;
            next[idx] = rp;
        }
        carry += wsum[15];
        __syncthreads();
    }
    if (t == 0) row_ptr[N_RXN] = carry;
}

// 1c. placement: slot = next[r]++ ; edges_sorted[slot] = {x_met[met], sto}
__global__ __launch_bounds__(256) void place_kernel(
    const float* __restrict__ x_met, const float* __restrict__ sto_sub,
    const int* __restrict__ met_sub, const int* __restrict__ rxn_sub,
    int* __restrict__ next, float2* __restrict__ edges_sorted)
{
    const int e = blockIdx.x * 256 + threadIdx.x;
    if (e >= E_SUB) return;
    const int r = rxn_sub[e];
    const int slot = atomicAdd(&next[r], 1);
    edges_sorted[slot] = make_float2(x_met[met_sub[e]], sto_sub[e]);
}

// 1d. WAVE-PER-REACTION gather + msg-MLP + rate-MLP + softplus -> v[N_RXN].
// 64 lanes read the reaction's contiguous edge segment (coalesced); each lane
// runs the 2->32tanh->16 msg MLP for its edge(s) into registers; butterfly
// shfl reduce h[16] across the wave; rate MLP split 1 hidden unit/lane.
// NOTE: launch_bounds (256,2) = 128 VGPR cap. (256,4)=64 VGPR spilled h[16]
// to scratch -> 4.9 GB of HBM spill writes, 3.7x regression (round 5).
__global__ __launch_bounds__(256, 2) void gather_rate_kernel(
    const float2* __restrict__ edges_sorted, const int* __restrict__ row_ptr,
    const float* __restrict__ W1m, const float* __restrict__ b1m,
    const float* __restrict__ W2m, const float* __restrict__ b2m,
    const float* __restrict__ W1r, const float* __restrict__ b1r,
    const float* __restrict__ W2r, const float* __restrict__ b2r,
    float* __restrict__ v)
{
    __shared__ float sW1m[2 * HIDDEN];
    __shared__ float sb1m[HIDDEN];
    __shared__ float sW2m[HIDDEN * MSG_DIM];
    __shared__ float sb2m[MSG_DIM];
    __shared__ float sW1r[MSG_DIM * HIDDEN];
    __shared__ float sb1r[HIDDEN];
    __shared__ float sW2r[HIDDEN];
    __shared__ float sb2r;
    const int t = threadIdx.x;
    if (t < 2 * HIDDEN) sW1m[t] = W1m[t];
    if (t < HIDDEN)     sb1m[t] = b1m[t];
    for (int i = t; i < HIDDEN * MSG_DIM; i += 256) sW2m[i] = W2m[i];
    if (t < MSG_DIM)    sb2m[t] = b2m[t];
    for (int i = t; i < MSG_DIM * HIDDEN; i += 256) sW1r[i] = W1r[i];
    if (t >= 64 && t < 64 + HIDDEN) { sb1r[t - 64] = b1r[t - 64]; sW2r[t - 64] = W2r[t - 64]; }
    if (t == 128) sb2r = b2r[0];
    __syncthreads();

    const int wv   = t >> 6;
    const int lane = t & 63;
    const int r    = blockIdx.x * 4 + wv;   // grid = N_RXN/4 exactly

    const int beg = row_ptr[r];
    const int end = row_ptr[r + 1];

    float h[MSG_DIM];
#pragma unroll
    for (int d = 0; d < MSG_DIM; ++d) h[d] = 0.0f;

    for (int i = beg + lane; i < end; i += 64) {
        const float2 xs = edges_sorted[i];
#pragma unroll
        for (int j = 0; j < HIDDEN; ++j) {
            const float hj =
                tanhf(fmaf(xs.x, sW1m[j], fmaf(xs.y, sW1m[HIDDEN + j], sb1m[j])));
#pragma unroll
            for (int d = 0; d < MSG_DIM; ++d)
                h[d] = fmaf(hj, sW2m[j * MSG_DIM + d], h[d]);
        }
    }

    // wave-reduce h[16] (butterfly; all lanes end with the segment sum)
#pragma unroll
    for (int off = 32; off >= 1; off >>= 1) {
#pragma unroll
        for (int d = 0; d < MSG_DIM; ++d)
            h[d] += __shfl_xor(h[d], off);
    }

    // fold per-edge +b2m: cnt * b2m
    const float cnt = (float)(end - beg);
#pragma unroll
    for (int d = 0; d < MSG_DIM; ++d) h[d] = fmaf(cnt, sb2m[d], h[d]);

    // rate MLP: lane j (j<32) computes hidden unit j; reduce over 32 lanes
    float part = 0.0f;
    if (lane < HIDDEN) {
        float z = sb1r[lane];
#pragma unroll
        for (int d = 0; d < MSG_DIM; ++d)
            z = fmaf(h[d], sW1r[d * HIDDEN + lane], z);
        part = tanhf(z) * sW2r[lane];
    }
#pragma unroll
    for (int off = 16; off >= 1; off >>= 1)
        part += __shfl_xor(part, off);

    if (lane == 0) {
        const float acc = part + sb2r;
        v[r] = fmaxf(acc, 0.0f) + log1pf(expf(-fabsf(acc)));
    }
}

// ---- Phase 2: per-all-edge contribution scattered into dxdt (4M f32 atomics).
__global__ __launch_bounds__(256) void contrib_scatter_kernel(
    const float* __restrict__ sto_all, const float* __restrict__ v,
    const int* __restrict__ met_all, const int* __restrict__ rxn_all,
    float* __restrict__ dxdt)
{
    const int e = blockIdx.x * 256 + threadIdx.x;
    if (e >= E_ALL) return;
    const float c = sto_all[e] * v[rxn_all[e]];
    unsafeAtomicAdd(dxdt + met_all[e], c);
}

extern "C" void kernel_launch(void* const* d_in, const int* in_sizes, int n_in,
                              void* d_out, int out_size, void* d_ws, size_t ws_size,
                              hipStream_t stream) {
    const float* x_met   = (const float*)d_in[0];
    const float* sto_sub = (const float*)d_in[1];
    const float* sto_all = (const float*)d_in[2];
    const float* W1m     = (const float*)d_in[3];
    const float* b1m     = (const float*)d_in[4];
    const float* W2m     = (const float*)d_in[5];
    const float* b2m     = (const float*)d_in[6];
    const float* W1r     = (const float*)d_in[7];
    const float* b1r     = (const float*)d_in[8];
    const float* W2r     = (const float*)d_in[9];
    const float* b2r     = (const float*)d_in[10];
    const int*   met_sub = (const int*)d_in[11];
    const int*   rxn_sub = (const int*)d_in[12];
    const int*   met_all = (const int*)d_in[13];
    const int*   rxn_all = (const int*)d_in[14];

    float* dxdt = (float*)d_out;             // [N_MET]
    float* v    = dxdt + N_MET;              // [N_RXN]

    // workspace layout
    char* ws = (char*)d_ws;
    int* count   = (int*)ws;                              ws += sizeof(int) * N_RXN;
    int* row_ptr = (int*)ws;                              ws += sizeof(int) * (N_RXN + 1);
    int* next    = (int*)ws;                              ws += sizeof(int) * N_RXN;
    float2* edges_sorted = (float2*)ws;                   // [E_SUB] = 16 MB

    hipMemsetAsync(count, 0, sizeof(int) * N_RXN, stream);
    hipMemsetAsync(dxdt, 0, sizeof(float) * N_MET, stream);

    hist_kernel<<<(E_SUB / 4 + 255) / 256, 256, 0, stream>>>(rxn_sub, count);
    scan_kernel<<<1, 1024, 0, stream>>>(count, row_ptr, next);
    place_kernel<<<(E_SUB + 255) / 256, 256, 0, stream>>>(
        x_met, sto_sub, met_sub, rxn_sub, next, edges_sorted);
    gather_rate_kernel<<<N_RXN / 4, 256, 0, stream>>>(
        edges_sorted, row_ptr, W1m, b1m, W2m, b2m, W1r, b1r, W2r, b2r, v);
    contrib_scatter_kernel<<<(E_ALL + 255) / 256, 256, 0, stream>>>(
        sto_all, v, met_all, rxn_all, dxdt);
}

// Round 7
// 698.079 us; speedup vs baseline: 6.2205x; 4.3119x over previous
//
#include <hip/hip_runtime.h>

#define N_MET 100000
#define N_RXN 50000
#define E_SUB 2000000
#define E_ALL 4000000
#define MSG_DIM 16
#define HIDDEN 32

// ---- Phase 1: build CSR of substrate edges by reaction (counting sort), ----
// ---- then wave-per-reaction gather-reduce. -----------------------------------

// 1a. histogram of rxn_sub (int4-vectorized reads; E_SUB % 4 == 0)
__global__ __launch_bounds__(256) void hist_kernel(
    const int* __restrict__ rxn_sub, int* __restrict__ count)
{
    const int i = blockIdx.x * 256 + threadIdx.x;
    if (i >= E_SUB / 4) return;
    const int4 r = ((const int4*)rxn_sub)[i];
    atomicAdd(&count[r.x], 1);
    atomicAdd(&count[r.y], 1);
    atomicAdd(&count[r.z], 1);
    atomicAdd(&count[r.w], 1);
}

// 1b. exclusive scan of count[N_RXN] -> row_ptr[N_RXN+1], and next = row_ptr.
__global__ __launch_bounds__(1024) void scan_kernel(
    const int* __restrict__ count, int* __restrict__ row_ptr,
    int* __restrict__ next)
{
    __shared__ int wsum[16];
    const int t = threadIdx.x;
    const int lane = t & 63;
    const int w = t >> 6;
    int carry = 0;
    for (int base = 0; base < N_RXN; base += 1024) {
        const int idx = base + t;
        const int val = (idx < N_RXN) ? count[idx] : 0;
        int x = val;
#pragma unroll
        for (int off = 1; off < 64; off <<= 1) {
            const int y = __shfl_up(x, off);
            if (lane >= off) x += y;
        }
        if (lane == 63) wsum[w] = x;
        __syncthreads();
        if (w == 0) {
            int s = (lane < 16) ? wsum[lane] : 0;
#pragma unroll
            for (int off = 1; off < 16; off <<= 1) {
                const int y = __shfl_up(s, off);
                if (lane >= off) s += y;
            }
            if (lane < 16) wsum[lane] = s;
        }
        __syncthreads();
        const int wexcl = (w > 0) ? wsum[w - 1] : 0;
        const int excl = wexcl + x - val;
        if (idx < N_RXN) {
            const int rp = carry + excl;
            row_ptr[idx] = rp;
            next[idx] = rp;
        }
        carry += wsum[15];
        __syncthreads();
    }
    if (t == 0) row_ptr[N_RXN] = carry;
}

// 1c. placement: slot = next[r]++ ; edges_sorted[slot] = {x_met[met], sto}
__global__ __launch_bounds__(256) void place_kernel(
    const float* __restrict__ x_met, const float* __restrict__ sto_sub,
    const int* __restrict__ met_sub, const int* __restrict__ rxn_sub,
    int* __restrict__ next, float2* __restrict__ edges_sorted)
{
    const int e = blockIdx.x * 256 + threadIdx.x;
    if (e >= E_SUB) return;
    const int r = rxn_sub[e];
    const int slot = atomicAdd(&next[r], 1);
    edges_sorted[slot] = make_float2(x_met[met_sub[e]], sto_sub[e]);
}

// 1d. WAVE-PER-REACTION gather + msg-MLP + rate-MLP + softplus -> v[N_RXN].
// 64 lanes read the reaction's contiguous edge segment (coalesced); each lane
// runs the 2->32tanh->16 msg MLP for its edge(s) into registers; butterfly
// shfl reduce h[16] across the wave; rate MLP split 1 hidden unit/lane.
// NOTE: j-loop is "#pragma unroll 2" — full unroll (32) hoists ~512 LDS weight
// loads, natural pressure ~256 VGPR, and any cap <=128 spills h[16] to scratch
// (rounds 5/6: 4.9/3.8 GB of HBM spill traffic). d-loops MUST stay fully
// unrolled so h[16] stays in registers.
__global__ __launch_bounds__(256, 2) void gather_rate_kernel(
    const float2* __restrict__ edges_sorted, const int* __restrict__ row_ptr,
    const float* __restrict__ W1m, const float* __restrict__ b1m,
    const float* __restrict__ W2m, const float* __restrict__ b2m,
    const float* __restrict__ W1r, const float* __restrict__ b1r,
    const float* __restrict__ W2r, const float* __restrict__ b2r,
    float* __restrict__ v)
{
    __shared__ float sW1m[2 * HIDDEN];
    __shared__ float sb1m[HIDDEN];
    __shared__ float sW2m[HIDDEN * MSG_DIM];
    __shared__ float sb2m[MSG_DIM];
    __shared__ float sW1r[MSG_DIM * HIDDEN];
    __shared__ float sb1r[HIDDEN];
    __shared__ float sW2r[HIDDEN];
    __shared__ float sb2r;
    const int t = threadIdx.x;
    if (t < 2 * HIDDEN) sW1m[t] = W1m[t];
    if (t < HIDDEN)     sb1m[t] = b1m[t];
    for (int i = t; i < HIDDEN * MSG_DIM; i += 256) sW2m[i] = W2m[i];
    if (t < MSG_DIM)    sb2m[t] = b2m[t];
    for (int i = t; i < MSG_DIM * HIDDEN; i += 256) sW1r[i] = W1r[i];
    if (t >= 64 && t < 64 + HIDDEN) { sb1r[t - 64] = b1r[t - 64]; sW2r[t - 64] = W2r[t - 64]; }
    if (t == 128) sb2r = b2r[0];
    __syncthreads();

    const int wv   = t >> 6;
    const int lane = t & 63;
    const int r    = blockIdx.x * 4 + wv;   // grid = N_RXN/4 exactly

    const int beg = row_ptr[r];
    const int end = row_ptr[r + 1];

    float h[MSG_DIM];
#pragma unroll
    for (int d = 0; d < MSG_DIM; ++d) h[d] = 0.0f;

    for (int i = beg + lane; i < end; i += 64) {
        const float2 xs = edges_sorted[i];
#pragma unroll 2
        for (int j = 0; j < HIDDEN; ++j) {
            const float hj =
                tanhf(fmaf(xs.x, sW1m[j], fmaf(xs.y, sW1m[HIDDEN + j], sb1m[j])));
#pragma unroll
            for (int d = 0; d < MSG_DIM; ++d)
                h[d] = fmaf(hj, sW2m[j * MSG_DIM + d], h[d]);
        }
    }

    // wave-reduce h[16] (butterfly; all lanes end with the segment sum)
#pragma unroll
    for (int off = 32; off >= 1; off >>= 1) {
#pragma unroll
        for (int d = 0; d < MSG_DIM; ++d)
            h[d] += __shfl_xor(h[d], off);
    }

    // fold per-edge +b2m: cnt * b2m
    const float cnt = (float)(end - beg);
#pragma unroll
    for (int d = 0; d < MSG_DIM; ++d) h[d] = fmaf(cnt, sb2m[d], h[d]);

    // rate MLP: lane j (j<32) computes hidden unit j; reduce over 32 lanes
    float part = 0.0f;
    if (lane < HIDDEN) {
        float z = sb1r[lane];
#pragma unroll
        for (int d = 0; d < MSG_DIM; ++d)
            z = fmaf(h[d], sW1r[d * HIDDEN + lane], z);
        part = tanhf(z) * sW2r[lane];
    }
#pragma unroll
    for (int off = 16; off >= 1; off >>= 1)
        part += __shfl_xor(part, off);

    if (lane == 0) {
        const float acc = part + sb2r;
        v[r] = fmaxf(acc, 0.0f) + log1pf(expf(-fabsf(acc)));
    }
}

// ---- Phase 2: per-all-edge contribution scattered into dxdt (4M f32 atomics).
__global__ __launch_bounds__(256) void contrib_scatter_kernel(
    const float* __restrict__ sto_all, const float* __restrict__ v,
    const int* __restrict__ met_all, const int* __restrict__ rxn_all,
    float* __restrict__ dxdt)
{
    const int e = blockIdx.x * 256 + threadIdx.x;
    if (e >= E_ALL) return;
    const float c = sto_all[e] * v[rxn_all[e]];
    unsafeAtomicAdd(dxdt + met_all[e], c);
}

extern "C" void kernel_launch(void* const* d_in, const int* in_sizes, int n_in,
                              void* d_out, int out_size, void* d_ws, size_t ws_size,
                              hipStream_t stream) {
    const float* x_met   = (const float*)d_in[0];
    const float* sto_sub = (const float*)d_in[1];
    const float* sto_all = (const float*)d_in[2];
    const float* W1m     = (const float*)d_in[3];
    const float* b1m     = (const float*)d_in[4];
    const float* W2m     = (const float*)d_in[5];
    const float* b2m     = (const float*)d_in[6];
    const float* W1r     = (const float*)d_in[7];
    const float* b1r     = (const float*)d_in[8];
    const float* W2r     = (const float*)d_in[9];
    const float* b2r     = (const float*)d_in[10];
    const int*   met_sub = (const int*)d_in[11];
    const int*   rxn_sub = (const int*)d_in[12];
    const int*   met_all = (const int*)d_in[13];
    const int*   rxn_all = (const int*)d_in[14];

    float* dxdt = (float*)d_out;             // [N_MET]
    float* v    = dxdt + N_MET;              // [N_RXN]

    // workspace layout
    char* ws = (char*)d_ws;
    int* count   = (int*)ws;                              ws += sizeof(int) * N_RXN;
    int* row_ptr = (int*)ws;                              ws += sizeof(int) * (N_RXN + 1);
    int* next    = (int*)ws;                              ws += sizeof(int) * N_RXN;
    float2* edges_sorted = (float2*)ws;                   // [E_SUB] = 16 MB

    hipMemsetAsync(count, 0, sizeof(int) * N_RXN, stream);
    hipMemsetAsync(dxdt, 0, sizeof(float) * N_MET, stream);

    hist_kernel<<<(E_SUB / 4 + 255) / 256, 256, 0, stream>>>(rxn_sub, count);
    scan_kernel<<<1, 1024, 0, stream>>>(count, row_ptr, next);
    place_kernel<<<(E_SUB + 255) / 256, 256, 0, stream>>>(
        x_met, sto_sub, met_sub, rxn_sub, next, edges_sorted);
    gather_rate_kernel<<<N_RXN / 4, 256, 0, stream>>>(
        edges_sorted, row_ptr, W1m, b1m, W2m, b2m, W1r, b1r, W2r, b2r, v);
    contrib_scatter_kernel<<<(E_ALL + 255) / 256, 256, 0, stream>>>(
        sto_all, v, met_all, rxn_all, dxdt);
}

// Round 8
// 631.695 us; speedup vs baseline: 6.8742x; 1.1051x over previous
//
#include <hip/hip_runtime.h>

#define N_MET 100000
#define N_RXN 50000
#define E_SUB 2000000
#define E_ALL 4000000
#define MSG_DIM 16
#define HIDDEN 32

// ---- Phase 1: build CSR of substrate edges by reaction (counting sort), ----
// ---- then wave-per-reaction gather-reduce. -----------------------------------

// 1a. histogram of rxn_sub + RANK CAPTURE: the atomic's return value is this
// edge's rank within its reaction -> place needs no atomics (halves build
// atomics; scattered-atomic service wall is ~19 G/s, rounds 1-3).
__global__ __launch_bounds__(256) void hist_rank_kernel(
    const int* __restrict__ rxn_sub, int* __restrict__ count,
    int* __restrict__ rank)
{
    const int i = blockIdx.x * 256 + threadIdx.x;
    if (i >= E_SUB / 4) return;
    const int4 r = ((const int4*)rxn_sub)[i];
    int4 k;
    k.x = atomicAdd(&count[r.x], 1);
    k.y = atomicAdd(&count[r.y], 1);
    k.z = atomicAdd(&count[r.z], 1);
    k.w = atomicAdd(&count[r.w], 1);
    ((int4*)rank)[i] = k;
}

// 1b. exclusive scan of count[N_RXN] -> row_ptr[N_RXN+1]. 4 elems/thread.
__global__ __launch_bounds__(1024) void scan_kernel(
    const int* __restrict__ count, int* __restrict__ row_ptr)
{
    __shared__ int wsum[16];
    const int t = threadIdx.x;
    const int lane = t & 63;
    const int w = t >> 6;
    int carry = 0;
    for (int base = 0; base < N_RXN; base += 4096) {
        const int i0 = base + t * 4;
        const int c0 = (i0 + 0 < N_RXN) ? count[i0 + 0] : 0;
        const int c1 = (i0 + 1 < N_RXN) ? count[i0 + 1] : 0;
        const int c2 = (i0 + 2 < N_RXN) ? count[i0 + 2] : 0;
        const int c3 = (i0 + 3 < N_RXN) ? count[i0 + 3] : 0;
        const int local = c0 + c1 + c2 + c3;
        int x = local;
#pragma unroll
        for (int off = 1; off < 64; off <<= 1) {
            const int y = __shfl_up(x, off);
            if (lane >= off) x += y;
        }
        if (lane == 63) wsum[w] = x;
        __syncthreads();
        if (w == 0) {
            int s = (lane < 16) ? wsum[lane] : 0;
#pragma unroll
            for (int off = 1; off < 16; off <<= 1) {
                const int y = __shfl_up(s, off);
                if (lane >= off) s += y;
            }
            if (lane < 16) wsum[lane] = s;
        }
        __syncthreads();
        const int excl = carry + ((w > 0) ? wsum[w - 1] : 0) + x - local;
        if (i0 + 0 < N_RXN) row_ptr[i0 + 0] = excl;
        if (i0 + 1 < N_RXN) row_ptr[i0 + 1] = excl + c0;
        if (i0 + 2 < N_RXN) row_ptr[i0 + 2] = excl + c0 + c1;
        if (i0 + 3 < N_RXN) row_ptr[i0 + 3] = excl + c0 + c1 + c2;
        carry += wsum[15];
        __syncthreads();
    }
    if (t == 0) row_ptr[N_RXN] = carry;   // == E_SUB
}

// 1c. placement (ATOMIC-FREE): slot = row_ptr[r] + rank[e].
__global__ __launch_bounds__(256) void place_kernel(
    const float* __restrict__ x_met, const float* __restrict__ sto_sub,
    const int* __restrict__ met_sub, const int* __restrict__ rxn_sub,
    const int* __restrict__ rank, const int* __restrict__ row_ptr,
    float2* __restrict__ edges_sorted)
{
    const int e = blockIdx.x * 256 + threadIdx.x;
    if (e >= E_SUB) return;
    const int slot = row_ptr[rxn_sub[e]] + rank[e];
    edges_sorted[slot] = make_float2(x_met[met_sub[e]], sto_sub[e]);
}

// 1d. WAVE-PER-REACTION gather + msg-MLP + rate-MLP + softplus -> v[N_RXN].
// NOTE: j-loop is "#pragma unroll 2" — full unroll (32) hoists ~512 LDS weight
// loads, natural pressure ~256 VGPR, and any cap <=128 spills h[16] to scratch
// (rounds 5/6: 4.9/3.8 GB of HBM spill traffic). d-loops MUST stay fully
// unrolled so h[16] stays in registers.
__global__ __launch_bounds__(256, 2) void gather_rate_kernel(
    const float2* __restrict__ edges_sorted, const int* __restrict__ row_ptr,
    const float* __restrict__ W1m, const float* __restrict__ b1m,
    const float* __restrict__ W2m, const float* __restrict__ b2m,
    const float* __restrict__ W1r, const float* __restrict__ b1r,
    const float* __restrict__ W2r, const float* __restrict__ b2r,
    float* __restrict__ v)
{
    __shared__ float sW1m[2 * HIDDEN];
    __shared__ float sb1m[HIDDEN];
    __shared__ float sW2m[HIDDEN * MSG_DIM];
    __shared__ float sb2m[MSG_DIM];
    __shared__ float sW1r[MSG_DIM * HIDDEN];
    __shared__ float sb1r[HIDDEN];
    __shared__ float sW2r[HIDDEN];
    __shared__ float sb2r;
    const int t = threadIdx.x;
    if (t < 2 * HIDDEN) sW1m[t] = W1m[t];
    if (t < HIDDEN)     sb1m[t] = b1m[t];
    for (int i = t; i < HIDDEN * MSG_DIM; i += 256) sW2m[i] = W2m[i];
    if (t < MSG_DIM)    sb2m[t] = b2m[t];
    for (int i = t; i < MSG_DIM * HIDDEN; i += 256) sW1r[i] = W1r[i];
    if (t >= 64 && t < 64 + HIDDEN) { sb1r[t - 64] = b1r[t - 64]; sW2r[t - 64] = W2r[t - 64]; }
    if (t == 128) sb2r = b2r[0];
    __syncthreads();

    const int wv   = t >> 6;
    const int lane = t & 63;
    const int r    = blockIdx.x * 4 + wv;   // grid = N_RXN/4 exactly

    const int beg = row_ptr[r];
    const int end = row_ptr[r + 1];

    float h[MSG_DIM];
#pragma unroll
    for (int d = 0; d < MSG_DIM; ++d) h[d] = 0.0f;

    for (int i = beg + lane; i < end; i += 64) {
        const float2 xs = edges_sorted[i];
#pragma unroll 2
        for (int j = 0; j < HIDDEN; ++j) {
            const float hj =
                tanhf(fmaf(xs.x, sW1m[j], fmaf(xs.y, sW1m[HIDDEN + j], sb1m[j])));
#pragma unroll
            for (int d = 0; d < MSG_DIM; ++d)
                h[d] = fmaf(hj, sW2m[j * MSG_DIM + d], h[d]);
        }
    }

    // wave-reduce h[16] (butterfly; all lanes end with the segment sum)
#pragma unroll
    for (int off = 32; off >= 1; off >>= 1) {
#pragma unroll
        for (int d = 0; d < MSG_DIM; ++d)
            h[d] += __shfl_xor(h[d], off);
    }

    // fold per-edge +b2m: cnt * b2m
    const float cnt = (float)(end - beg);
#pragma unroll
    for (int d = 0; d < MSG_DIM; ++d) h[d] = fmaf(cnt, sb2m[d], h[d]);

    // rate MLP: lane j (j<32) computes hidden unit j; reduce over 32 lanes
    float part = 0.0f;
    if (lane < HIDDEN) {
        float z = sb1r[lane];
#pragma unroll
        for (int d = 0; d < MSG_DIM; ++d)
            z = fmaf(h[d], sW1r[d * HIDDEN + lane], z);
        part = tanhf(z) * sW2r[lane];
    }
#pragma unroll
    for (int off = 16; off >= 1; off >>= 1)
        part += __shfl_xor(part, off);

    if (lane == 0) {
        const float acc = part + sb2r;
        v[r] = fmaxf(acc, 0.0f) + log1pf(expf(-fabsf(acc)));
    }
}

// ---- Phase 2: per-all-edge contribution scattered into dxdt.
// 4M scattered f32 atomics @ ~19 G/s service wall ≈ 210 µs — structurally
// minimal: any CSR build for this side also needs >= 4M atomics, and random
// single-float destinations can't be line-grouped without that sort.
__global__ __launch_bounds__(256) void contrib_scatter_kernel(
    const float* __restrict__ sto_all, const float* __restrict__ v,
    const int* __restrict__ met_all, const int* __restrict__ rxn_all,
    float* __restrict__ dxdt)
{
    const int e = blockIdx.x * 256 + threadIdx.x;
    if (e >= E_ALL) return;
    const float c = sto_all[e] * v[rxn_all[e]];
    unsafeAtomicAdd(dxdt + met_all[e], c);
}

extern "C" void kernel_launch(void* const* d_in, const int* in_sizes, int n_in,
                              void* d_out, int out_size, void* d_ws, size_t ws_size,
                              hipStream_t stream) {
    const float* x_met   = (const float*)d_in[0];
    const float* sto_sub = (const float*)d_in[1];
    const float* sto_all = (const float*)d_in[2];
    const float* W1m     = (const float*)d_in[3];
    const float* b1m     = (const float*)d_in[4];
    const float* W2m     = (const float*)d_in[5];
    const float* b2m     = (const float*)d_in[6];
    const float* W1r     = (const float*)d_in[7];
    const float* b1r     = (const float*)d_in[8];
    const float* W2r     = (const float*)d_in[9];
    const float* b2r     = (const float*)d_in[10];
    const int*   met_sub = (const int*)d_in[11];
    const int*   rxn_sub = (const int*)d_in[12];
    const int*   met_all = (const int*)d_in[13];
    const int*   rxn_all = (const int*)d_in[14];

    float* dxdt = (float*)d_out;             // [N_MET]
    float* v    = dxdt + N_MET;              // [N_RXN]

    // workspace layout (16B-aligned chunks)
    char* ws = (char*)d_ws;
    int* count   = (int*)ws;                 ws += sizeof(int) * N_RXN;        // 200000 B
    int* rank    = (int*)ws;                 ws += sizeof(int) * E_SUB;        // 8 MB
    int* row_ptr = (int*)ws;                 ws += ((sizeof(int) * (N_RXN + 1) + 15) / 16) * 16;
    float2* edges_sorted = (float2*)ws;      // [E_SUB] = 16 MB

    hipMemsetAsync(count, 0, sizeof(int) * N_RXN, stream);
    hipMemsetAsync(dxdt, 0, sizeof(float) * N_MET, stream);

    hist_rank_kernel<<<(E_SUB / 4 + 255) / 256, 256, 0, stream>>>(
        rxn_sub, count, rank);
    scan_kernel<<<1, 1024, 0, stream>>>(count, row_ptr);
    place_kernel<<<(E_SUB + 255) / 256, 256, 0, stream>>>(
        x_met, sto_sub, met_sub, rxn_sub, rank, row_ptr, edges_sorted);
    gather_rate_kernel<<<N_RXN / 4, 256, 0, stream>>>(
        edges_sorted, row_ptr, W1m, b1m, W2m, b2m, W1r, b1r, W2r, b2r, v);
    contrib_scatter_kernel<<<(E_ALL + 255) / 256, 256, 0, stream>>>(
        sto_all, v, met_all, rxn_all, dxdt);
}

// Round 9
// 619.839 us; speedup vs baseline: 7.0057x; 1.0191x over previous
//
#include <hip/hip_runtime.h>

#define N_MET 100000
#define N_RXN 50000
#define E_SUB 2000000
#define E_ALL 4000000
#define MSG_DIM 16
#define HIDDEN 32
#define N_XCD 8

// Physical XCD id of the executing wave (gfx950: 0..7). Wave-uniform.
__device__ __forceinline__ unsigned xcc_id() {
    unsigned x;
    asm volatile("s_getreg_b32 %0, hwreg(HW_REG_XCC_ID)" : "=s"(x));
    return x & (N_XCD - 1);
}

// ---- Phase 1: build CSR of substrate edges by reaction (counting sort), ----
// ---- then wave-per-reaction gather-reduce. -----------------------------------

// 1a. histogram of rxn_sub + RANK CAPTURE: the atomic's return value is this
// edge's rank within its reaction -> place needs no atomics.
__global__ __launch_bounds__(256) void hist_rank_kernel(
    const int* __restrict__ rxn_sub, int* __restrict__ count,
    int* __restrict__ rank)
{
    const int i = blockIdx.x * 256 + threadIdx.x;
    if (i >= E_SUB / 4) return;
    const int4 r = ((const int4*)rxn_sub)[i];
    int4 k;
    k.x = atomicAdd(&count[r.x], 1);
    k.y = atomicAdd(&count[r.y], 1);
    k.z = atomicAdd(&count[r.z], 1);
    k.w = atomicAdd(&count[r.w], 1);
    ((int4*)rank)[i] = k;
}

// 1b. exclusive scan of count[N_RXN] -> row_ptr[N_RXN+1]. 4 elems/thread.
__global__ __launch_bounds__(1024) void scan_kernel(
    const int* __restrict__ count, int* __restrict__ row_ptr)
{
    __shared__ int wsum[16];
    const int t = threadIdx.x;
    const int lane = t & 63;
    const int w = t >> 6;
    int carry = 0;
    for (int base = 0; base < N_RXN; base += 4096) {
        const int i0 = base + t * 4;
        const int c0 = (i0 + 0 < N_RXN) ? count[i0 + 0] : 0;
        const int c1 = (i0 + 1 < N_RXN) ? count[i0 + 1] : 0;
        const int c2 = (i0 + 2 < N_RXN) ? count[i0 + 2] : 0;
        const int c3 = (i0 + 3 < N_RXN) ? count[i0 + 3] : 0;
        const int local = c0 + c1 + c2 + c3;
        int x = local;
#pragma unroll
        for (int off = 1; off < 64; off <<= 1) {
            const int y = __shfl_up(x, off);
            if (lane >= off) x += y;
        }
        if (lane == 63) wsum[w] = x;
        __syncthreads();
        if (w == 0) {
            int s = (lane < 16) ? wsum[lane] : 0;
#pragma unroll
            for (int off = 1; off < 16; off <<= 1) {
                const int y = __shfl_up(s, off);
                if (lane >= off) s += y;
            }
            if (lane < 16) wsum[lane] = s;
        }
        __syncthreads();
        const int excl = carry + ((w > 0) ? wsum[w - 1] : 0) + x - local;
        if (i0 + 0 < N_RXN) row_ptr[i0 + 0] = excl;
        if (i0 + 1 < N_RXN) row_ptr[i0 + 1] = excl + c0;
        if (i0 + 2 < N_RXN) row_ptr[i0 + 2] = excl + c0 + c1;
        if (i0 + 3 < N_RXN) row_ptr[i0 + 3] = excl + c0 + c1 + c2;
        carry += wsum[15];
        __syncthreads();
    }
    if (t == 0) row_ptr[N_RXN] = carry;   // == E_SUB
}

// 1c. placement (ATOMIC-FREE): slot = row_ptr[r] + rank[e].
__global__ __launch_bounds__(256) void place_kernel(
    const float* __restrict__ x_met, const float* __restrict__ sto_sub,
    const int* __restrict__ met_sub, const int* __restrict__ rxn_sub,
    const int* __restrict__ rank, const int* __restrict__ row_ptr,
    float2* __restrict__ edges_sorted)
{
    const int e = blockIdx.x * 256 + threadIdx.x;
    if (e >= E_SUB) return;
    const int slot = row_ptr[rxn_sub[e]] + rank[e];
    edges_sorted[slot] = make_float2(x_met[met_sub[e]], sto_sub[e]);
}

// 1d. WAVE-PER-REACTION gather + msg-MLP + rate-MLP + softplus -> v[N_RXN].
// NOTE: j-loop is "#pragma unroll 2" — full unroll (32) hoists ~512 LDS weight
// loads, natural pressure ~256 VGPR, and any cap <=128 spills h[16] to scratch
// (rounds 5/6: 4.9/3.8 GB of HBM spill traffic). d-loops MUST stay fully
// unrolled so h[16] stays in registers.
__global__ __launch_bounds__(256, 2) void gather_rate_kernel(
    const float2* __restrict__ edges_sorted, const int* __restrict__ row_ptr,
    const float* __restrict__ W1m, const float* __restrict__ b1m,
    const float* __restrict__ W2m, const float* __restrict__ b2m,
    const float* __restrict__ W1r, const float* __restrict__ b1r,
    const float* __restrict__ W2r, const float* __restrict__ b2r,
    float* __restrict__ v)
{
    __shared__ float sW1m[2 * HIDDEN];
    __shared__ float sb1m[HIDDEN];
    __shared__ float sW2m[HIDDEN * MSG_DIM];
    __shared__ float sb2m[MSG_DIM];
    __shared__ float sW1r[MSG_DIM * HIDDEN];
    __shared__ float sb1r[HIDDEN];
    __shared__ float sW2r[HIDDEN];
    __shared__ float sb2r;
    const int t = threadIdx.x;
    if (t < 2 * HIDDEN) sW1m[t] = W1m[t];
    if (t < HIDDEN)     sb1m[t] = b1m[t];
    for (int i = t; i < HIDDEN * MSG_DIM; i += 256) sW2m[i] = W2m[i];
    if (t < MSG_DIM)    sb2m[t] = b2m[t];
    for (int i = t; i < MSG_DIM * HIDDEN; i += 256) sW1r[i] = W1r[i];
    if (t >= 64 && t < 64 + HIDDEN) { sb1r[t - 64] = b1r[t - 64]; sW2r[t - 64] = W2r[t - 64]; }
    if (t == 128) sb2r = b2r[0];
    __syncthreads();

    const int wv   = t >> 6;
    const int lane = t & 63;
    const int r    = blockIdx.x * 4 + wv;   // grid = N_RXN/4 exactly

    const int beg = row_ptr[r];
    const int end = row_ptr[r + 1];

    float h[MSG_DIM];
#pragma unroll
    for (int d = 0; d < MSG_DIM; ++d) h[d] = 0.0f;

    for (int i = beg + lane; i < end; i += 64) {
        const float2 xs = edges_sorted[i];
#pragma unroll 2
        for (int j = 0; j < HIDDEN; ++j) {
            const float hj =
                tanhf(fmaf(xs.x, sW1m[j], fmaf(xs.y, sW1m[HIDDEN + j], sb1m[j])));
#pragma unroll
            for (int d = 0; d < MSG_DIM; ++d)
                h[d] = fmaf(hj, sW2m[j * MSG_DIM + d], h[d]);
        }
    }

    // wave-reduce h[16] (butterfly; all lanes end with the segment sum)
#pragma unroll
    for (int off = 32; off >= 1; off >>= 1) {
#pragma unroll
        for (int d = 0; d < MSG_DIM; ++d)
            h[d] += __shfl_xor(h[d], off);
    }

    // fold per-edge +b2m: cnt * b2m
    const float cnt = (float)(end - beg);
#pragma unroll
    for (int d = 0; d < MSG_DIM; ++d) h[d] = fmaf(cnt, sb2m[d], h[d]);

    // rate MLP: lane j (j<32) computes hidden unit j; reduce over 32 lanes
    float part = 0.0f;
    if (lane < HIDDEN) {
        float z = sb1r[lane];
#pragma unroll
        for (int d = 0; d < MSG_DIM; ++d)
            z = fmaf(h[d], sW1r[d * HIDDEN + lane], z);
        part = tanhf(z) * sW2r[lane];
    }
#pragma unroll
    for (int off = 16; off >= 1; off >>= 1)
        part += __shfl_xor(part, off);

    if (lane == 0) {
        const float acc = part + sb2r;
        v[r] = fmaxf(acc, 0.0f) + log1pf(expf(-fabsf(acc)));
    }
}

// ---- Phase 2: per-all-edge contribution into a PER-XCD replica of dxdt.
// Device-scope atomics bypass the 8 non-coherent L2s and hit the memory-side
// RMW wall (~19 G/s, rounds 1-8). Replica i is touched ONLY by XCD i (id read
// from HW_REG_XCC_ID), so workgroup-scope atomics may execute in the local L2.
__global__ __launch_bounds__(256) void contrib_scatter_kernel(
    const float* __restrict__ sto_all, const float* __restrict__ v,
    const int* __restrict__ met_all, const int* __restrict__ rxn_all,
    float* __restrict__ d_rep)
{
    const int e = blockIdx.x * 256 + threadIdx.x;
    if (e >= E_ALL) return;
    const float c = sto_all[e] * v[rxn_all[e]];
    float* dst = d_rep + (size_t)xcc_id() * N_MET + met_all[e];
    __hip_atomic_fetch_add(dst, c, __ATOMIC_RELAXED, __HIP_MEMORY_SCOPE_WORKGROUP);
}

// ---- Fold the per-XCD replicas into dxdt (N_MET % 4 == 0). ----
__global__ __launch_bounds__(256) void dxdt_reduce_kernel(
    const float* __restrict__ d_rep, float* __restrict__ dxdt)
{
    const int i = blockIdx.x * 256 + threadIdx.x;
    if (i >= N_MET / 4) return;
    float4 acc = make_float4(0.f, 0.f, 0.f, 0.f);
#pragma unroll
    for (int x = 0; x < N_XCD; ++x) {
        const float4 r = ((const float4*)(d_rep + (size_t)x * N_MET))[i];
        acc.x += r.x; acc.y += r.y; acc.z += r.z; acc.w += r.w;
    }
    ((float4*)dxdt)[i] = acc;
}

extern "C" void kernel_launch(void* const* d_in, const int* in_sizes, int n_in,
                              void* d_out, int out_size, void* d_ws, size_t ws_size,
                              hipStream_t stream) {
    const float* x_met   = (const float*)d_in[0];
    const float* sto_sub = (const float*)d_in[1];
    const float* sto_all = (const float*)d_in[2];
    const float* W1m     = (const float*)d_in[3];
    const float* b1m     = (const float*)d_in[4];
    const float* W2m     = (const float*)d_in[5];
    const float* b2m     = (const float*)d_in[6];
    const float* W1r     = (const float*)d_in[7];
    const float* b1r     = (const float*)d_in[8];
    const float* W2r     = (const float*)d_in[9];
    const float* b2r     = (const float*)d_in[10];
    const int*   met_sub = (const int*)d_in[11];
    const int*   rxn_sub = (const int*)d_in[12];
    const int*   met_all = (const int*)d_in[13];
    const int*   rxn_all = (const int*)d_in[14];

    float* dxdt = (float*)d_out;             // [N_MET]
    float* v    = dxdt + N_MET;              // [N_RXN]

    // workspace layout (16B-aligned chunks)
    char* ws = (char*)d_ws;
    int* count   = (int*)ws;                 ws += sizeof(int) * N_RXN;        // 200 KB
    int* rank    = (int*)ws;                 ws += sizeof(int) * E_SUB;        // 8 MB
    int* row_ptr = (int*)ws;                 ws += ((sizeof(int) * (N_RXN + 1) + 15) / 16) * 16;
    float2* edges_sorted = (float2*)ws;      ws += sizeof(float2) * E_SUB;     // 16 MB
    float* d_rep = (float*)ws;               // [N_XCD][N_MET] = 3.2 MB

    hipMemsetAsync(count, 0, sizeof(int) * N_RXN, stream);
    hipMemsetAsync(d_rep, 0, sizeof(float) * N_XCD * N_MET, stream);

    hist_rank_kernel<<<(E_SUB / 4 + 255) / 256, 256, 0, stream>>>(
        rxn_sub, count, rank);
    scan_kernel<<<1, 1024, 0, stream>>>(count, row_ptr);
    place_kernel<<<(E_SUB + 255) / 256, 256, 0, stream>>>(
        x_met, sto_sub, met_sub, rxn_sub, rank, row_ptr, edges_sorted);
    gather_rate_kernel<<<N_RXN / 4, 256, 0, stream>>>(
        edges_sorted, row_ptr, W1m, b1m, W2m, b2m, W1r, b1r, W2r, b2r, v);
    contrib_scatter_kernel<<<(E_ALL + 255) / 256, 256, 0, stream>>>(
        sto_all, v, met_all, rxn_all, d_rep);
    dxdt_reduce_kernel<<<(N_MET / 4 + 255) / 256, 256, 0, stream>>>(
        d_rep, dxdt);
}